// Round 1
// baseline (124.011 us; speedup 1.0000x reference)
//
#include <hip/hip_runtime.h>

// Problem constants (match reference setup_inputs).
#define BB 4
#define CC 128
#define CE 64
#define VV 4096
#define NLEV 14   // MAX_LEVELS

// Workspace:
//   wsort [BB*VV] float : edge weight of node at SORTED position i
//   giInv [BB*VV] int   : levelpos of pixel v
//   cpl   [BB*VV] int2  : {cp (levelpos of parent), sorted idx i} at levelpos k
//   offs  [BB*16] int   : level start offsets

__device__ __forceinline__ void lds_fadd(float* p, float v) {
    unsafeAtomicAdd(p, v);   // ds_add_f32 on gfx950 LDS
}

// ---------------------------------------------------------------------------
// K1 (fused): blocks [0,BB)           : per-batch counting sort -> tables
//             blocks [BB, BB+BB*64)   : edge weights in SORTED order
//             (independent of each other -> run concurrently in one launch)
//
// Sort block rewritten round 1: the old version did 2x4096 contended LDS
// atomics (hist + returning cursor) onto <=14 addresses -> ~25-35 us of
// serialization on ONE CU = prep's critical path. Replaced with wave-
// aggregated ballot counting (0 atomics for hist, ~640 uncontended atomics
// for rank). Within-level rank order is arbitrary (sum over children), so
// any consistent assignment is valid.
// ---------------------------------------------------------------------------
__global__ __launch_bounds__(256) void prep_kernel(
    const float* __restrict__ embed,
    const int* __restrict__ sorted_index,
    const int* __restrict__ sorted_parent,
    const int* __restrict__ node_level,
    float* __restrict__ wsort,
    int*   __restrict__ giInv,
    int2*  __restrict__ cpl,
    int*   __restrict__ offs)
{
    int tid = threadIdx.x;
    if (blockIdx.x < BB) {
        int b = blockIdx.x;
        __shared__ int pos_s[VV];            // 16 KB: i -> levelpos k
        __shared__ int whist[4][16];
        __shared__ int cursor[NLEV];
        __shared__ int offSh[NLEV + 1];
        const int* lev = node_level    + b * VV;
        const int* si  = sorted_index  + b * VV;
        const int* par = sorted_parent + b * VV;
        int lane = tid & 63;
        int w    = tid >> 6;

        // ---- pass A: per-wave histogram via ballot, counts land in lane d
        int dreg[16], sreg[16];
        int myc = 0;
        #pragma unroll
        for (int t = 0; t < 4; ++t) {
            int idx = tid + t * 256;
            int4 dv = ((const int4*)lev)[idx];
            int4 sv = ((const int4*)si)[idx];
            #pragma unroll
            for (int j = 0; j < 4; ++j) {
                int d = (&dv.x)[j]; d = d < NLEV - 1 ? d : NLEV - 1;
                dreg[t * 4 + j] = d;
                sreg[t * 4 + j] = (&sv.x)[j];
                #pragma unroll
                for (int dd = 0; dd < NLEV; ++dd) {
                    unsigned long long m = __ballot(d == dd);
                    myc += (lane == dd) ? (int)__popcll(m) : 0;
                }
            }
        }
        if (lane < 16) whist[w][lane] = myc;   // lanes 14,15 write 0
        __syncthreads();
        if (tid == 0) {
            int acc = 0;
            for (int d = 0; d < NLEV; ++d) {
                int h = whist[0][d] + whist[1][d] + whist[2][d] + whist[3][d];
                offSh[d] = acc; cursor[d] = acc; acc += h;
            }
            offSh[NLEV] = acc;
        }
        __syncthreads();
        if (tid <= NLEV) offs[b * 16 + tid] = offSh[tid];

        // ---- pass B: rank assignment, one atomic per (wave, level present)
        int kreg[16];
        #pragma unroll
        for (int t = 0; t < 4; ++t) {
            #pragma unroll
            for (int j = 0; j < 4; ++j) {
                int i = 4 * (tid + t * 256) + j;
                int d = dreg[t * 4 + j];
                int k = 0;
                #pragma unroll
                for (int dd = 0; dd < NLEV; ++dd) {
                    unsigned long long m = __ballot(d == dd);
                    if (m) {
                        int leader = (int)__ffsll((unsigned long long)m) - 1;
                        int base = 0;
                        if (lane == leader) base = atomicAdd(&cursor[dd], (int)__popcll(m));
                        base = __shfl(base, leader, 64);
                        if (d == dd) k = base + (int)__popcll(m & ((1ull << lane) - 1ull));
                    }
                }
                kreg[t * 4 + j] = k;
                pos_s[i] = k;
                giInv[b * VV + sreg[t * 4 + j]] = k;
            }
        }
        __syncthreads();

        // ---- pass C: emit cpl from the i-side (coalesced par reads,
        //      scattered 8B writes; pos_s[p] is the only LDS gather)
        #pragma unroll
        for (int t = 0; t < 4; ++t) {
            int idx = tid + t * 256;
            int4 pv = ((const int4*)par)[idx];
            #pragma unroll
            for (int j = 0; j < 4; ++j) {
                int i = 4 * idx + j;
                int p = (&pv.x)[j];
                cpl[b * VV + kreg[t * 4 + j]] = make_int2(pos_s[p], i);
            }
        }
    } else {
        // weight: block = 64 nodes; wave w covers ce chunk [16w, 16w+16).
        __shared__ float part[4][64];
        int bb   = blockIdx.x - BB;
        int b    = bb >> 6;
        int n0   = (bb & 63) << 6;
        int lane = tid & 63;
        int w    = tid >> 6;
        int i    = n0 + lane;
        int vi = sorted_index[b * VV + i];
        int p  = sorted_parent[b * VV + i];
        int vp = sorted_index[b * VV + p];
        const float* eb = embed + (size_t)b * CE * VV;
        float acc = 0.f;
        #pragma unroll
        for (int r = 0; r < 16; ++r) {
            int ce = w * 16 + r;
            float d = eb[ce * VV + vi] - eb[ce * VV + vp];
            acc = fmaf(d, d, acc);
        }
        part[w][lane] = acc;
        __syncthreads();
        if (w == 0) {
            float d2 = part[0][lane] + part[1][lane] + part[2][lane] + part[3][lane];
            wsort[b * VV + i] = __expf(-d2);
        }
    }
}

// ---------------------------------------------------------------------------
// K2: tree filter, TWO channels per block + shared nrm chain. 256 blocks,
//     512 threads (8 waves/CU), 64 KB LDS. vs one-channel blocks: LDS atomic
//     total -25%, cw/giInv staging traffic -50%, nrm chains 128->64 per batch.
//     cw packs {w_hi20, cp12}; val & nrm use the SAME truncated w so the
//     final division cancels most of the perturbation.
// ---------------------------------------------------------------------------
__global__ __launch_bounds__(512) void tree2_kernel(
    const float* __restrict__ feat,
    const float* __restrict__ wsort,
    const int*  __restrict__ giInv,
    const int2* __restrict__ cpl,
    const int*  __restrict__ offs,
    float* __restrict__ out)
{
    __shared__ float val0[VV];   // 16 KB  channel c0 by levelpos
    __shared__ float val1[VV];   // 16 KB  channel c0+1
    __shared__ float nrm[VV];    // 16 KB  shared normalizer
    __shared__ int   cw[VV];     // 16 KB  packed {w_hi20, cp12}
    __shared__ int   offS[16];
    int b   = blockIdx.x >> 6;   // 64 channel-pairs per batch
    int c0  = (blockIdx.x & 63) << 1;
    int tid = threadIdx.x;

    const int2*  cplB = cpl   + b * VV;
    const int*   ivB  = giInv + b * VV;
    const float* wsB  = wsort + b * VV;
    const float* f0   = feat + ((size_t)(b * CC + c0)) * VV;
    const float* f1   = f0 + VV;

    if (tid < 16) offS[tid] = offs[b * 16 + tid];

    // stage + pack: coalesced int2 reads; w gather hits L1/L2 (16 KB/batch)
    #pragma unroll
    for (int t = 0; t < 8; ++t) {
        int k = tid + t * 512;
        int2 x = cplB[k];
        int wb = __float_as_int(wsB[x.y]);
        cw[k] = (wb & 0xFFFFF000) | x.x;
    }

    // init: coalesced float4/int4 reads, scattered b32 LDS writes; keep kk
    int4 kkR[2];
    #pragma unroll
    for (int t = 0; t < 2; ++t) {
        int idx = tid + t * 512;
        int4   kk = ((const int4*)ivB)[idx];
        float4 a  = ((const float4*)f0)[idx];
        float4 bq = ((const float4*)f1)[idx];
        kkR[t] = kk;
        val0[kk.x] = a.x;  val0[kk.y] = a.y;  val0[kk.z] = a.z;  val0[kk.w] = a.w;
        val1[kk.x] = bq.x; val1[kk.y] = bq.y; val1[kk.z] = bq.z; val1[kk.w] = bq.w;
        nrm[kk.x] = 1.f;   nrm[kk.y] = 1.f;   nrm[kk.z] = 1.f;   nrm[kk.w] = 1.f;
    }
    __syncthreads();

    // upward: parents of level d are exactly level d-1 -> phase-safe atomics
    for (int d = NLEV - 1; d >= 1; --d) {
        int s = offS[d], e = offS[d + 1];
        if (s == e) continue;                 // offS uniform -> safe skip
        for (int k = s + tid; k < e; k += 512) {
            int x = cw[k];
            float w = __int_as_float(x & 0xFFFFF000);
            int  cp = x & 0xFFF;
            lds_fadd(&val0[cp], w * val0[k]);
            lds_fadd(&val1[cp], w * val1[k]);
            lds_fadd(&nrm[cp],  w * nrm[k]);
        }
        __syncthreads();
    }

    // downward: in place; parent (level d-1) final before level d reads it
    for (int d = 1; d <= NLEV - 1; ++d) {
        int s = offS[d], e = offS[d + 1];
        if (s == e) continue;
        for (int k = s + tid; k < e; k += 512) {
            int x = cw[k];
            float w = __int_as_float(x & 0xFFFFF000);
            int  cp = x & 0xFFF;
            float u0 = val0[k], u1 = val1[k], un = nrm[k];
            val0[k] = fmaf(w, fmaf(-w, u0, val0[cp]), u0);
            val1[k] = fmaf(w, fmaf(-w, u1, val1[cp]), u1);
            nrm[k]  = fmaf(w, fmaf(-w, un, nrm[cp]),  un);
        }
        __syncthreads();
    }

    // epilogue: scattered b32 LDS reads, coalesced float4 stores, 2 channels
    float* o0 = out + ((size_t)(b * CC + c0)) * VV;
    float* o1 = o0 + VV;
    #pragma unroll
    for (int t = 0; t < 2; ++t) {
        int idx = tid + t * 512;
        int4 kk = kkR[t];
        float i0 = __fdividef(1.f, nrm[kk.x]);
        float i1 = __fdividef(1.f, nrm[kk.y]);
        float i2 = __fdividef(1.f, nrm[kk.z]);
        float i3 = __fdividef(1.f, nrm[kk.w]);
        float4 r0, r1;
        r0.x = val0[kk.x] * i0; r0.y = val0[kk.y] * i1;
        r0.z = val0[kk.z] * i2; r0.w = val0[kk.w] * i3;
        r1.x = val1[kk.x] * i0; r1.y = val1[kk.y] * i1;
        r1.z = val1[kk.z] * i2; r1.w = val1[kk.w] * i3;
        ((float4*)o0)[idx] = r0;
        ((float4*)o1)[idx] = r1;
    }
}

extern "C" void kernel_launch(void* const* d_in, const int* in_sizes, int n_in,
                              void* d_out, int out_size, void* d_ws, size_t ws_size,
                              hipStream_t stream) {
    const float* feat          = (const float*)d_in[0];
    const float* embed         = (const float*)d_in[1];
    const int*   sorted_index  = (const int*)d_in[2];
    const int*   sorted_parent = (const int*)d_in[3];
    const int*   node_level    = (const int*)d_in[4];
    float* out = (float*)d_out;

    char* ws = (char*)d_ws;
    const size_t A = (size_t)BB * VV * 4;     // 64 KB
    float* wsort = (float*)(ws);              // 64 KB
    int*   giInv = (int*)  (ws + A);          // 64 KB
    int2*  cpl   = (int2*) (ws + 2 * A);      // 128 KB
    int*   offs  = (int*)  (ws + 4 * A);      // 256 B

    prep_kernel<<<BB + BB * 64, 256, 0, stream>>>(
        embed, sorted_index, sorted_parent, node_level, wsort, giInv, cpl, offs);

    tree2_kernel<<<BB * CC / 2, 512, 0, stream>>>(
        feat, wsort, giInv, cpl, offs, out);
}

// Round 2
// 103.318 us; speedup vs baseline: 1.2003x; 1.2003x over previous
//
#include <hip/hip_runtime.h>

// Problem constants (match reference setup_inputs).
#define BB 4
#define CC 128
#define CE 64
#define VV 4096
#define NLEV 14   // MAX_LEVELS

// Workspace:
//   wsort [BB*VV] float : edge weight of node at SORTED position i
//   giInv [BB*VV] int   : levelpos of pixel v
//   cpl   [BB*VV] int2  : {cp (levelpos of parent), sorted idx i} at levelpos k
//   offs  [BB*16] int   : level start offsets

__device__ __forceinline__ void lds_fadd(float* p, float v) {
    unsafeAtomicAdd(p, v);   // ds_add_f32 on gfx950 LDS
}

// ---------------------------------------------------------------------------
// K1 (fused): blocks [0,BB)           : per-batch counting sort -> tables
//             blocks [BB, BB+BB*64)   : edge weights in SORTED order
//
// Sort block history:
//   r0: contended LDS atomics (4096 hist + 4096 returning cursor onto <=14
//       addrs, one CU) -- prep critical path.
//   r1: ballot rank -- WORSE (+13us): 224 dependent ballot->atomic->shfl
//       iterations per wave ~ 30K-cycle serial chain.
//   r2 (this): register counts + wave-scan + direct rank. Zero atomics,
//       zero ballots, no serial LDS chains. Each thread owns 16 CONSECUTIVE
//       elements; in-thread rank via 120 static compares; cross-thread
//       offsets via one shfl_up scan per level (4 levels/wave).
//       Within-level order becomes deterministic pixel order -- semantics-
//       preserving (up-pass is an order-free sum, down-pass per-node).
// ---------------------------------------------------------------------------
__global__ __launch_bounds__(256) void prep_kernel(
    const float* __restrict__ embed,
    const int* __restrict__ sorted_index,
    const int* __restrict__ sorted_parent,
    const int* __restrict__ node_level,
    float* __restrict__ wsort,
    int*   __restrict__ giInv,
    int2*  __restrict__ cpl,
    int*   __restrict__ offs)
{
    int tid = threadIdx.x;
    if (blockIdx.x < BB) {
        int b = blockIdx.x;
        __shared__ int  pos_s[VV];            // 16 KB: i -> levelpos k
        __shared__ int4 cntv[NLEV * 64];      // 14 KB: [level][thread] counts/offsets
        __shared__ int  tot[NLEV];
        __shared__ int  offSh[NLEV + 1];
        int* cnt = (int*)cntv;
        const int* lev = node_level    + b * VV;
        const int* si  = sorted_index  + b * VV;
        const int* par = sorted_parent + b * VV;
        int lane = tid & 63;
        int w    = tid >> 6;

        // ---- load: thread owns elements i = 16*tid + m, m in [0,16)
        int dreg[16], sreg[16];
        #pragma unroll
        for (int t = 0; t < 4; ++t) {
            int4 dv = ((const int4*)lev)[tid * 4 + t];
            int4 sv = ((const int4*)si)[tid * 4 + t];
            #pragma unroll
            for (int j = 0; j < 4; ++j) {
                int d = (&dv.x)[j]; d = d < NLEV - 1 ? d : NLEV - 1;
                dreg[t * 4 + j] = d;
                sreg[t * 4 + j] = (&sv.x)[j];
            }
        }

        // ---- in-thread rank (register-only, static unroll)
        int rank[16];
        #pragma unroll
        for (int m = 0; m < 16; ++m) {
            int r = 0;
            #pragma unroll
            for (int m2 = 0; m2 < m; ++m2) r += (dreg[m2] == dreg[m]) ? 1 : 0;
            rank[m] = r;
        }

        // ---- per-thread per-level counts (register compares, clean writes)
        #pragma unroll
        for (int d = 0; d < NLEV; ++d) {
            int c = 0;
            #pragma unroll
            for (int m = 0; m < 16; ++m) c += (dreg[m] == d) ? 1 : 0;
            cnt[d * 256 + tid] = c;
        }
        __syncthreads();

        // ---- exclusive scan over threads, per level; wave w does levels w,w+4,...
        for (int d = w; d < NLEV; d += 4) {
            int base = d * 64 + lane;          // int4 granularity
            int4 cv = cntv[base];
            int ls = cv.x + cv.y + cv.z + cv.w;
            int x = ls;
            #pragma unroll
            for (int off = 1; off < 64; off <<= 1) {
                int y = __shfl_up(x, off, 64);
                if (lane >= off) x += y;
            }
            int excl = x - ls;
            int4 ov;
            ov.x = excl;
            ov.y = excl + cv.x;
            ov.z = excl + cv.x + cv.y;
            ov.w = excl + cv.x + cv.y + cv.z;
            cntv[base] = ov;
            if (lane == 63) tot[d] = x;
        }
        __syncthreads();
        if (tid == 0) {
            int acc = 0;
            for (int d = 0; d < NLEV; ++d) { offSh[d] = acc; acc += tot[d]; }
            offSh[NLEV] = acc;
        }
        __syncthreads();
        if (tid <= NLEV) offs[b * 16 + tid] = offSh[tid];

        // ---- rank assignment: pure LDS reads, no RMW
        int kreg[16];
        #pragma unroll
        for (int m = 0; m < 16; ++m) {
            int d = dreg[m];
            int k = offSh[d] + cnt[d * 256 + tid] + rank[m];
            kreg[m] = k;
            pos_s[16 * tid + m] = k;
            giInv[b * VV + sreg[m]] = k;
        }
        __syncthreads();

        // ---- emit cpl from the i-side (pos_s[p] is the only LDS gather)
        #pragma unroll
        for (int t = 0; t < 4; ++t) {
            int4 pv = ((const int4*)par)[tid * 4 + t];
            #pragma unroll
            for (int j = 0; j < 4; ++j) {
                int m = t * 4 + j;
                int p = (&pv.x)[j];
                cpl[b * VV + kreg[m]] = make_int2(pos_s[p], 16 * tid + m);
            }
        }
    } else {
        // weight: block = 64 nodes; wave w covers ce chunk [16w, 16w+16).
        __shared__ float part[4][64];
        int bb   = blockIdx.x - BB;
        int b    = bb >> 6;
        int n0   = (bb & 63) << 6;
        int lane = tid & 63;
        int w    = tid >> 6;
        int i    = n0 + lane;
        int vi = sorted_index[b * VV + i];
        int p  = sorted_parent[b * VV + i];
        int vp = sorted_index[b * VV + p];
        const float* eb = embed + (size_t)b * CE * VV;
        float acc = 0.f;
        #pragma unroll
        for (int r = 0; r < 16; ++r) {
            int ce = w * 16 + r;
            float d = eb[ce * VV + vi] - eb[ce * VV + vp];
            acc = fmaf(d, d, acc);
        }
        part[w][lane] = acc;
        __syncthreads();
        if (w == 0) {
            float d2 = part[0][lane] + part[1][lane] + part[2][lane] + part[3][lane];
            wsort[b * VV + i] = __expf(-d2);
        }
    }
}

// ---------------------------------------------------------------------------
// K2: tree filter, TWO channels per block + shared nrm chain. 256 blocks,
//     512 threads (8 waves/CU), 64 KB LDS. vs one-channel blocks: LDS atomic
//     total -25%, cw/giInv staging traffic -50%, nrm chains 128->64 per batch.
//     cw packs {w_hi20, cp12}; val & nrm use the SAME truncated w so the
//     final division cancels most of the perturbation.
// ---------------------------------------------------------------------------
__global__ __launch_bounds__(512) void tree2_kernel(
    const float* __restrict__ feat,
    const float* __restrict__ wsort,
    const int*  __restrict__ giInv,
    const int2* __restrict__ cpl,
    const int*  __restrict__ offs,
    float* __restrict__ out)
{
    __shared__ float val0[VV];   // 16 KB  channel c0 by levelpos
    __shared__ float val1[VV];   // 16 KB  channel c0+1
    __shared__ float nrm[VV];    // 16 KB  shared normalizer
    __shared__ int   cw[VV];     // 16 KB  packed {w_hi20, cp12}
    __shared__ int   offS[16];
    int b   = blockIdx.x >> 6;   // 64 channel-pairs per batch
    int c0  = (blockIdx.x & 63) << 1;
    int tid = threadIdx.x;

    const int2*  cplB = cpl   + b * VV;
    const int*   ivB  = giInv + b * VV;
    const float* wsB  = wsort + b * VV;
    const float* f0   = feat + ((size_t)(b * CC + c0)) * VV;
    const float* f1   = f0 + VV;

    if (tid < 16) offS[tid] = offs[b * 16 + tid];

    // stage + pack: coalesced int2 reads; w gather hits L1/L2 (16 KB/batch)
    #pragma unroll
    for (int t = 0; t < 8; ++t) {
        int k = tid + t * 512;
        int2 x = cplB[k];
        int wb = __float_as_int(wsB[x.y]);
        cw[k] = (wb & 0xFFFFF000) | x.x;
    }

    // init: coalesced float4/int4 reads, scattered b32 LDS writes; keep kk
    int4 kkR[2];
    #pragma unroll
    for (int t = 0; t < 2; ++t) {
        int idx = tid + t * 512;
        int4   kk = ((const int4*)ivB)[idx];
        float4 a  = ((const float4*)f0)[idx];
        float4 bq = ((const float4*)f1)[idx];
        kkR[t] = kk;
        val0[kk.x] = a.x;  val0[kk.y] = a.y;  val0[kk.z] = a.z;  val0[kk.w] = a.w;
        val1[kk.x] = bq.x; val1[kk.y] = bq.y; val1[kk.z] = bq.z; val1[kk.w] = bq.w;
        nrm[kk.x] = 1.f;   nrm[kk.y] = 1.f;   nrm[kk.z] = 1.f;   nrm[kk.w] = 1.f;
    }
    __syncthreads();

    // upward: parents of level d are exactly level d-1 -> phase-safe atomics
    for (int d = NLEV - 1; d >= 1; --d) {
        int s = offS[d], e = offS[d + 1];
        if (s == e) continue;                 // offS uniform -> safe skip
        for (int k = s + tid; k < e; k += 512) {
            int x = cw[k];
            float w = __int_as_float(x & 0xFFFFF000);
            int  cp = x & 0xFFF;
            lds_fadd(&val0[cp], w * val0[k]);
            lds_fadd(&val1[cp], w * val1[k]);
            lds_fadd(&nrm[cp],  w * nrm[k]);
        }
        __syncthreads();
    }

    // downward: in place; parent (level d-1) final before level d reads it
    for (int d = 1; d <= NLEV - 1; ++d) {
        int s = offS[d], e = offS[d + 1];
        if (s == e) continue;
        for (int k = s + tid; k < e; k += 512) {
            int x = cw[k];
            float w = __int_as_float(x & 0xFFFFF000);
            int  cp = x & 0xFFF;
            float u0 = val0[k], u1 = val1[k], un = nrm[k];
            val0[k] = fmaf(w, fmaf(-w, u0, val0[cp]), u0);
            val1[k] = fmaf(w, fmaf(-w, u1, val1[cp]), u1);
            nrm[k]  = fmaf(w, fmaf(-w, un, nrm[cp]),  un);
        }
        __syncthreads();
    }

    // epilogue: scattered b32 LDS reads, coalesced float4 stores, 2 channels
    float* o0 = out + ((size_t)(b * CC + c0)) * VV;
    float* o1 = o0 + VV;
    #pragma unroll
    for (int t = 0; t < 2; ++t) {
        int idx = tid + t * 512;
        int4 kk = kkR[t];
        float i0 = __fdividef(1.f, nrm[kk.x]);
        float i1 = __fdividef(1.f, nrm[kk.y]);
        float i2 = __fdividef(1.f, nrm[kk.z]);
        float i3 = __fdividef(1.f, nrm[kk.w]);
        float4 r0, r1;
        r0.x = val0[kk.x] * i0; r0.y = val0[kk.y] * i1;
        r0.z = val0[kk.z] * i2; r0.w = val0[kk.w] * i3;
        r1.x = val1[kk.x] * i0; r1.y = val1[kk.y] * i1;
        r1.z = val1[kk.z] * i2; r1.w = val1[kk.w] * i3;
        ((float4*)o0)[idx] = r0;
        ((float4*)o1)[idx] = r1;
    }
}

extern "C" void kernel_launch(void* const* d_in, const int* in_sizes, int n_in,
                              void* d_out, int out_size, void* d_ws, size_t ws_size,
                              hipStream_t stream) {
    const float* feat          = (const float*)d_in[0];
    const float* embed         = (const float*)d_in[1];
    const int*   sorted_index  = (const int*)d_in[2];
    const int*   sorted_parent = (const int*)d_in[3];
    const int*   node_level    = (const int*)d_in[4];
    float* out = (float*)d_out;

    char* ws = (char*)d_ws;
    const size_t A = (size_t)BB * VV * 4;     // 64 KB
    float* wsort = (float*)(ws);              // 64 KB
    int*   giInv = (int*)  (ws + A);          // 64 KB
    int2*  cpl   = (int2*) (ws + 2 * A);      // 128 KB
    int*   offs  = (int*)  (ws + 4 * A);      // 256 B

    prep_kernel<<<BB + BB * 64, 256, 0, stream>>>(
        embed, sorted_index, sorted_parent, node_level, wsort, giInv, cpl, offs);

    tree2_kernel<<<BB * CC / 2, 512, 0, stream>>>(
        feat, wsort, giInv, cpl, offs, out);
}